// Round 7
// baseline (264.501 us; speedup 1.0000x reference)
//
#include <hip/hip_runtime.h>
#include <hip/hip_bf16.h>
#include <math.h>

#define BATCH 2
#define NQ    13125
#define MQ    26250   // BATCH*NQ
#define DM    256
#define NH    8
#define HDIM  32
#define NL    3
#define NP    4
#define NTOK  13125   // value tokens per batch (10000+2500+625)

typedef __attribute__((ext_vector_type(8))) short bf16x8;
typedef __attribute__((ext_vector_type(8))) unsigned short u16x8;
typedef __attribute__((ext_vector_type(4))) float f32x4;

__device__ __forceinline__ short f2bf(float f) {
    unsigned u = __float_as_uint(f);
    unsigned r = (u + 0x7FFFu + ((u >> 16) & 1u)) >> 16;
    return (short)r;
}
__device__ __forceinline__ float bf2f(unsigned short u) {
    return __uint_as_float((unsigned)u << 16);
}

// async global->LDS, 16B per lane. LDS dest must be wave-uniform base + lane*16.
__device__ __forceinline__ void gld_lds16(const short* g, short* l) {
    __builtin_amdgcn_global_load_lds(
        (const __attribute__((address_space(1))) unsigned int*)g,
        (__attribute__((address_space(3))) unsigned int*)l, 16, 0, 0);
}

// ---------------- weight prep: Wt[n][k] bf16 <- W[k][n] fp32 (K=256), + zero pad ----------------
// layout: Wt_val rows 0..255 | Wt_off 384 rows: Wo 0..191, Wa 192..287, pad 288..383 | Wt_out 256
__global__ __launch_bounds__(256) void wprep_kernel(const float* __restrict__ Wv,
                                                    const float* __restrict__ Wo,
                                                    const float* __restrict__ Wa,
                                                    const float* __restrict__ Wu,
                                                    short* __restrict__ Wt)
{
    const int w = blockIdx.y;
    const int Ns[5]   = {256, 192, 96, 256, 96};
    const int Offs[5] = {0, 65536, 114688, 163840, 139264};
    const int N = Ns[w];
    const int flat = blockIdx.x * 256 + threadIdx.x;
    const int n = flat >> 8, k = flat & 255;
    if (n >= N) return;
    if (w == 4) { Wt[139264 + n * 256 + k] = 0; return; }
    const float* W = (w == 0) ? Wv : ((w == 1) ? Wo : ((w == 2) ? Wa : Wu));
    Wt[Offs[w] + n * 256 + k] = f2bf(W[k * N + n]);
}

// ---------------- activation convert fp32 -> bf16; values into concatenated vcat layout ------
__global__ __launch_bounds__(256) void cvt_kernel(const float* __restrict__ q,
                                                  const float* __restrict__ v0,
                                                  const float* __restrict__ v1,
                                                  const float* __restrict__ v2,
                                                  short* __restrict__ qb,
                                                  short* __restrict__ vcat)
{
    const int t = blockIdx.y;
    const int sz4[4] = {MQ * 64, 2 * 10000 * 64, 2 * 2500 * 64, 2 * 625 * 64};
    const int i = blockIdx.x * 256 + threadIdx.x;
    if (i >= sz4[t]) return;
    const int row = i >> 6, c = i & 63;
    const float* src = (t == 0) ? q : ((t == 1) ? v0 : ((t == 2) ? v1 : v2));
    int orow;
    short* dst;
    if (t == 0)      { orow = row;                                        dst = qb; }
    else if (t == 1) { orow = (row / 10000) * NTOK + (row % 10000);       dst = vcat; }
    else if (t == 2) { orow = (row / 2500) * NTOK + 10000 + (row % 2500); dst = vcat; }
    else             { orow = (row / 625) * NTOK + 12500 + (row % 625);   dst = vcat; }
    float4 v = ((const float4*)src)[i];
    short4 o;
    o.x = f2bf(v.x); o.y = f2bf(v.y); o.z = f2bf(v.z); o.w = f2bf(v.w);
    ((short4*)dst)[orow * 64 + c] = o;
}

// ---------------- GEMM core: 64(M)x128(N) tile, K=256, ONE barrier ----------------
// A staged to LDS (64x256 bf16, 16B chunks XOR-swizzled: pos p of row r holds chunk p^(r&31));
// B (Wt, [N][256]) loaded straight from global (L2-hot), K fully unrolled -> no in-loop barriers.
__device__ __forceinline__ void gemm_core(const short* __restrict__ A,
                                          const short* __restrict__ Wt,
                                          int m0, int M, int n0,
                                          f32x4 acc[2][4], short* As)
{
    const int tid  = threadIdx.x;
    const int lane = tid & 63;
    const int wave = tid >> 6;

#pragma unroll
    for (int it = 0; it < 8; ++it) {
        const int g   = it * 256 + tid;
        const int row = g >> 5;
        const int p   = g & 31;
        const int c   = p ^ (row & 31);
        if (m0 + row < M)
            gld_lds16(A + (size_t)(m0 + row) * 256 + c * 8, As + (size_t)g * 8);
    }
    __syncthreads();

    const int wm = (wave & 1) * 32;
    const int wn = (wave >> 1) * 64;
    const int ml = lane & 15;
    const int kq = lane >> 4;

#pragma unroll
    for (int ks = 0; ks < 8; ++ks) {
        const int cb = ks * 4;
        bf16x8 af[2], bfr[4];
#pragma unroll
        for (int ti = 0; ti < 2; ++ti) {
            const int r = wm + ti * 16 + ml;
            const int p = (cb + kq) ^ (r & 31);
            af[ti] = *(const bf16x8*)&As[r * 256 + p * 8];
        }
#pragma unroll
        for (int tj = 0; tj < 4; ++tj) {
            const int r = n0 + wn + tj * 16 + ml;
            bfr[tj] = *(const bf16x8*)(Wt + (size_t)r * 256 + ks * 32 + kq * 8);
        }
#pragma unroll
        for (int ti = 0; ti < 2; ++ti)
#pragma unroll
            for (int tj = 0; tj < 4; ++tj)
                acc[ti][tj] = __builtin_amdgcn_mfma_f32_16x16x32_bf16(af[ti], bfr[tj], acc[ti][tj], 0, 0, 0);
    }
}

// fused vproj + offs/logits: gridDim.y = 5 (y<2: vproj n-halves; y>=2: fused-QKV n-thirds)
__global__ __launch_bounds__(256) void fgemm_kernel(const short* __restrict__ vcat,
                                                    const short* __restrict__ qbf,
                                                    const short* __restrict__ Wt_val,
                                                    const short* __restrict__ Wt_off,
                                                    const float* __restrict__ b_val,
                                                    const float* __restrict__ b_off,
                                                    const float* __restrict__ b_attn,
                                                    short* __restrict__ vws,
                                                    float* __restrict__ offs,
                                                    float* __restrict__ lgts)
{
    __shared__ short As[64 * 256];
    const int y  = blockIdx.y;
    const int m0 = blockIdx.x * 64;
    const bool isv = (y < 2);
    const short* A  = isv ? vcat : qbf;
    const short* Wt = isv ? Wt_val : Wt_off;
    const int n0 = isv ? y * 128 : (y - 2) * 128;

    f32x4 acc[2][4] = {};
    gemm_core(A, Wt, m0, MQ, n0, acc, As);

    const int tid  = threadIdx.x;
    const int lane = tid & 63;
    const int wave = tid >> 6;
    const int wm   = (wave & 1) * 32;
    const int wn   = (wave >> 1) * 64;
    const int ml   = lane & 15;
    const int kq   = lane >> 4;

#pragma unroll
    for (int tj = 0; tj < 4; ++tj) {
        const int gn = n0 + wn + tj * 16 + ml;
#pragma unroll
        for (int ti = 0; ti < 2; ++ti) {
#pragma unroll
            for (int r = 0; r < 4; ++r) {
                const int gm = m0 + wm + ti * 16 + kq * 4 + r;
                if (gm >= MQ) continue;
                const float v = acc[ti][tj][r];
                if (isv) {
                    vws[(size_t)gm * 256 + gn] = f2bf(v + b_val[gn]);
                } else {
                    if (gn < 192)      offs[(size_t)gm * 192 + gn]        = v + b_off[gn];
                    else if (gn < 288) lgts[(size_t)gm * 96 + (gn - 192)] = v + b_attn[gn - 192];
                }
            }
        }
    }
}

// output projection: A=mid(bf16) -> out fp32
__global__ __launch_bounds__(256) void ogemm_kernel(const short* __restrict__ A,
                                                    const short* __restrict__ Wt,
                                                    const float* __restrict__ bias,
                                                    float* __restrict__ C)
{
    __shared__ short As[64 * 256];
    const int m0 = blockIdx.x * 64;
    const int n0 = blockIdx.y * 128;

    f32x4 acc[2][4] = {};
    gemm_core(A, Wt, m0, MQ, n0, acc, As);

    const int tid  = threadIdx.x;
    const int lane = tid & 63;
    const int wave = tid >> 6;
    const int wm   = (wave & 1) * 32;
    const int wn   = (wave >> 1) * 64;
    const int ml   = lane & 15;
    const int kq   = lane >> 4;

#pragma unroll
    for (int tj = 0; tj < 4; ++tj) {
        const int gn = n0 + wn + tj * 16 + ml;
#pragma unroll
        for (int ti = 0; ti < 2; ++ti) {
#pragma unroll
            for (int r = 0; r < 4; ++r) {
                const int gm = m0 + wm + ti * 16 + kq * 4 + r;
                if (gm >= MQ) continue;
                C[(size_t)gm * 256 + gn] = acc[ti][tj][r] + bias[gn];
            }
        }
    }
}

// ---------------- sampling: 8 queries/block (256 thr), 32 lanes/query, 16B bf16 gathers --------
__global__ __launch_bounds__(256) void sample_kernel(const short* __restrict__ vws,
                                                     const float* __restrict__ offs,
                                                     const float* __restrict__ logits,
                                                     const float* __restrict__ refp,
                                                     short* __restrict__ mid)
{
    const int q0  = blockIdx.x * 8;
    const int tid = threadIdx.x;

    __shared__ float  s_lg[8][96];
    __shared__ float  s_ref[8][6];
    __shared__ float  s_stat[8][NH][2];
    __shared__ float4 s_w[8][96];
    __shared__ int4   s_i[8][96];   // byte offsets (row*512)

    // Phase A: stage logits + refs
    for (int idx = tid; idx < 768; idx += 256) {
        const int qq = idx / 96, s = idx % 96;
        if (q0 + qq < MQ) s_lg[qq][s] = logits[(size_t)(q0 + qq) * 96 + s];
    }
    if (tid < 48) {
        const int qq = tid / 6, j = tid % 6;
        if (q0 + qq < MQ) s_ref[qq][j] = refp[(size_t)(q0 + qq) * 6 + j];
    }
    __syncthreads();

    // Phase B: per-head softmax stats
    if (tid < 64) {
        const int qq = tid >> 3, h = tid & 7;
        if (q0 + qq < MQ) {
            float mx = -1e30f;
#pragma unroll
            for (int i = 0; i < 12; ++i) mx = fmaxf(mx, s_lg[qq][h * 12 + i]);
            float ssum = 0.f;
#pragma unroll
            for (int i = 0; i < 12; ++i) ssum += expf(s_lg[qq][h * 12 + i] - mx);
            s_stat[qq][h][0] = mx;
            s_stat[qq][h][1] = 1.f / ssum;
        }
    }
    __syncthreads();

    // Phase C: folded corner weights + byte-offset indices
    for (int idx = tid; idx < 768; idx += 256) {
        const int qq = idx / 96, s = idx % 96;
        const int q  = q0 + qq;
        if (q >= MQ) continue;
        const int b  = q / NQ;
        const int h  = s / 12, i = s % 12;
        const int l  = i >> 2, p = i & 3;

        const int Hs[3] = {100, 50, 25};
        const int Wz[3] = {100, 50, 25};
        const int Lo[3] = {0, 10000, 12500};
        const int Wl = Wz[l], Hl = Hs[l];
        const float fW = (float)Wl, fH = (float)Hl;

        const float aw = expf(s_lg[qq][s] - s_stat[qq][h][0]) * s_stat[qq][h][1];

        const int oi = (((h * NL) + l) * NP + p) * 2;
        const float2 offp = *(const float2*)(offs + (size_t)q * 192 + oi);
        const float rx = s_ref[qq][l * 2 + 0];
        const float ry = s_ref[qq][l * 2 + 1];

        const float x = (rx + offp.x / fW) * fW - 0.5f;
        const float y = (ry + offp.y / fH) * fH - 0.5f;
        const float x0f = floorf(x), y0f = floorf(y);
        const int   x0 = (int)x0f,  y0 = (int)y0f;
        const float wx1 = x - x0f, wy1 = y - y0f;
        const float wx0 = 1.f - wx1, wy0 = 1.f - wy1;

        const bool xin0 = (x0 >= 0) && (x0 < Wl);
        const bool xin1 = (x0 + 1 >= 0) && (x0 + 1 < Wl);
        const bool yin0 = (y0 >= 0) && (y0 < Hl);
        const bool yin1 = (y0 + 1 >= 0) && (y0 + 1 < Hl);

        const int cx0 = min(max(x0, 0), Wl - 1);
        const int cx1 = min(max(x0 + 1, 0), Wl - 1);
        const int cy0 = min(max(y0, 0), Hl - 1);
        const int cy1 = min(max(y0 + 1, 0), Hl - 1);

        const int base = b * NTOK + Lo[l];
        int4 idxv;
        idxv.x = (base + cy0 * Wl + cx0) * 512;
        idxv.y = (base + cy0 * Wl + cx1) * 512;
        idxv.z = (base + cy1 * Wl + cx0) * 512;
        idxv.w = (base + cy1 * Wl + cx1) * 512;

        float4 w;
        w.x = (xin0 && yin0) ? aw * wx0 * wy0 : 0.f;
        w.y = (xin1 && yin0) ? aw * wx1 * wy0 : 0.f;
        w.z = (xin0 && yin1) ? aw * wx0 * wy1 : 0.f;
        w.w = (xin1 && yin1) ? aw * wx1 * wy1 : 0.f;

        s_w[qq][s] = w;
        s_i[qq][s] = idxv;
    }
    __syncthreads();

    // Phase D: gather-FMA, 32 lanes/query, 8 bf16 channels per lane (16B loads)
    {
        const int qq = tid >> 5;
        const int q  = q0 + qq;
        if (q < MQ) {
            const int r  = tid & 31;
            const int h  = r >> 2;
            const int c8 = (r & 3) * 8;
            const int ch = h * HDIM + c8;
            const char* vb = (const char*)vws + (size_t)ch * 2;

            float a[8] = {};
#pragma unroll
            for (int s = 0; s < 12; ++s) {
                const float4 w  = s_w[qq][h * 12 + s];
                const int4   id = s_i[qq][h * 12 + s];
                const u16x8 u0 = *(const u16x8*)(vb + id.x);
                const u16x8 u1 = *(const u16x8*)(vb + id.y);
                const u16x8 u2 = *(const u16x8*)(vb + id.z);
                const u16x8 u3 = *(const u16x8*)(vb + id.w);
#pragma unroll
                for (int j = 0; j < 8; ++j)
                    a[j] += w.x * bf2f(u0[j]) + w.y * bf2f(u1[j]) + w.z * bf2f(u2[j]) + w.w * bf2f(u3[j]);
            }
            union { u16x8 v; unsigned short s[8]; } o;
#pragma unroll
            for (int j = 0; j < 8; ++j) o.s[j] = (unsigned short)f2bf(a[j]);
            *(u16x8*)(mid + (size_t)q * DM + ch) = o.v;
        }
    }
}

// ---------------------------------------------------------------------------------------------
extern "C" void kernel_launch(void* const* d_in, const int* in_sizes, int n_in,
                              void* d_out, int out_size, void* d_ws, size_t ws_size,
                              hipStream_t stream)
{
    const float* query  = (const float*)d_in[0];
    const float* refp   = (const float*)d_in[1];
    const float* v0     = (const float*)d_in[2];
    const float* v1     = (const float*)d_in[3];
    const float* v2     = (const float*)d_in[4];
    const float* W_val  = (const float*)d_in[5];
    const float* b_val  = (const float*)d_in[6];
    const float* W_off  = (const float*)d_in[7];
    const float* b_off  = (const float*)d_in[8];
    const float* W_attn = (const float*)d_in[9];
    const float* b_attn = (const float*)d_in[10];
    const float* W_out  = (const float*)d_in[11];
    const float* b_out  = (const float*)d_in[12];
    float* out = (float*)d_out;

    float* ws   = (float*)d_ws;
    float* offs = ws;                                    // MQ*192 f32
    float* lgts = offs + (size_t)MQ * 192;               // MQ*96 f32
    short* vws  = (short*)(lgts + (size_t)MQ * 96);      // MQ*256 bf16 (projected values)
    short* mid  = vws + (size_t)MQ * DM;                 // MQ*256 bf16
    short* qbf  = mid + (size_t)MQ * DM;                 // MQ*256 bf16
    short* vcat = qbf + (size_t)MQ * DM;                 // MQ*256 bf16 (raw values, concat layout)
    short* Wt   = vcat + (size_t)MQ * DM;                // 229376 bf16
    short* Wt_val = Wt;                                  // rows 0..255
    short* Wt_off = Wt + 65536;                          // 384 rows: off|attn|pad
    short* Wt_out = Wt + 163840;                         // 256 rows

    // 0a. weights -> bf16 transposed (+ zero pad rows 288..383 of fused block)
    {
        dim3 grid(256, 5);
        wprep_kernel<<<grid, 256, 0, stream>>>(W_val, W_off, W_attn, W_out, Wt);
    }
    // 0b. activations -> bf16 (query + concatenated values)
    {
        dim3 grid((MQ * 64 + 255) / 256, 4);
        cvt_kernel<<<grid, 256, 0, stream>>>(query, v0, v1, v2, qbf, vcat);
    }
    // 1+2. fused: value projection (y=0,1) + offsets/logits (y=2,3,4)
    {
        dim3 grid((MQ + 63) / 64, 5);
        fgemm_kernel<<<grid, 256, 0, stream>>>(vcat, qbf, Wt_val, Wt_off,
                                               b_val, b_off, b_attn, vws, offs, lgts);
    }
    // 3. softmax + bilinear sampling (8 q/block) -> mid (bf16)
    sample_kernel<<<(MQ + 7) / 8, 256, 0, stream>>>(vws, offs, lgts, refp, mid);
    // 4. output projection -> out (fp32)
    {
        dim3 grid((MQ + 63) / 64, 2);
        ogemm_kernel<<<grid, 256, 0, stream>>>(mid, Wt_out, b_out, out);
    }
}

// Round 8
// 228.685 us; speedup vs baseline: 1.1566x; 1.1566x over previous
//
#include <hip/hip_runtime.h>
#include <hip/hip_bf16.h>
#include <math.h>

#define BATCH 2
#define NQ    13125
#define MQ    26250   // BATCH*NQ
#define DM    256
#define NH    8
#define HDIM  32
#define NL    3
#define NP    4
#define NTOK  13125   // value tokens per batch (10000+2500+625)

typedef __attribute__((ext_vector_type(8))) short bf16x8;
typedef __attribute__((ext_vector_type(4))) float f32x4;

__device__ __forceinline__ short f2bf(float f) {
    unsigned u = __float_as_uint(f);
    unsigned r = (u + 0x7FFFu + ((u >> 16) & 1u)) >> 16;
    return (short)r;
}
__device__ __forceinline__ float bf2f(unsigned short u) {
    return __uint_as_float((unsigned)u << 16);
}

// async global->LDS, 16B per lane. LDS dest must be wave-uniform base + lane*16.
__device__ __forceinline__ void gld_lds16(const short* g, short* l) {
    __builtin_amdgcn_global_load_lds(
        (const __attribute__((address_space(1))) unsigned int*)g,
        (__attribute__((address_space(3))) unsigned int*)l, 16, 0, 0);
}

// ---------------- prep: fused weight transpose->bf16 AND activation convert ----------------
// blocks [0,1280): weights; blocks [1280, 1280+13125): activations (q + vcat)
// Wt layout: Wt_val rows 0..255 | Wt_off 384 rows (off 0..191, attn 192..287, pad 288..383) | Wt_out
__global__ __launch_bounds__(256) void prep_kernel(const float* __restrict__ Wv,
                                                   const float* __restrict__ Wo,
                                                   const float* __restrict__ Wa,
                                                   const float* __restrict__ Wu,
                                                   const float* __restrict__ q,
                                                   const float* __restrict__ v0,
                                                   const float* __restrict__ v1,
                                                   const float* __restrict__ v2,
                                                   short* __restrict__ Wt,
                                                   short* __restrict__ qb,
                                                   short* __restrict__ vcat)
{
    const int bid = blockIdx.x;
    const int tid = threadIdx.x;
    if (bid < 1280) {
        // weights: w = bid>>8, xb = bid&255
        const int w  = bid >> 8;
        const int Ns[5]   = {256, 192, 96, 256, 96};
        const int Offs[5] = {0, 65536, 114688, 163840, 139264};
        const int N = Ns[w];
        const int flat = (bid & 255) * 256 + tid;
        const int n = flat >> 8, k = flat & 255;
        if (n >= N) return;
        if (w == 4) { Wt[139264 + n * 256 + k] = 0; return; }
        const float* W = (w == 0) ? Wv : ((w == 1) ? Wo : ((w == 2) ? Wa : Wu));
        Wt[Offs[w] + n * 256 + k] = f2bf(W[k * N + n]);
    } else {
        // activations: flat float4 index over [q | v0 | v1 | v2]
        const int i_flat = (bid - 1280) * 256 + tid;   // < 3,360,000 exactly
        int i, t;
        if (i_flat < 1680000)      { t = 0; i = i_flat; }
        else if (i_flat < 2960000) { t = 1; i = i_flat - 1680000; }
        else if (i_flat < 3280000) { t = 2; i = i_flat - 2960000; }
        else                       { t = 3; i = i_flat - 3280000; }
        const int row = i >> 6, c = i & 63;
        const float* src = (t == 0) ? q : ((t == 1) ? v0 : ((t == 2) ? v1 : v2));
        int orow;
        short* dst;
        if (t == 0)      { orow = row;                                        dst = qb; }
        else if (t == 1) { orow = (row / 10000) * NTOK + (row % 10000);       dst = vcat; }
        else if (t == 2) { orow = (row / 2500) * NTOK + 10000 + (row % 2500); dst = vcat; }
        else             { orow = (row / 625) * NTOK + 12500 + (row % 625);   dst = vcat; }
        float4 v = ((const float4*)src)[i];
        short4 o;
        o.x = f2bf(v.x); o.y = f2bf(v.y); o.z = f2bf(v.z); o.w = f2bf(v.w);
        ((short4*)dst)[orow * 64 + c] = o;
    }
}

// ---------------- 128x128-tile bf16 MFMA GEMM core (R6 internals, known-good) ----------------
// A bf16 [MQ][256], Wt bf16 [..][256]; LDS no-pad + XOR k-granule swizzle; glds width-16.
__device__ __forceinline__ void gemm_core128(const short* __restrict__ A,
                                             const short* __restrict__ Wt,
                                             int m0, int n0,
                                             f32x4 (&acc)[4][4],
                                             short* As, short* Bs)
{
    const int tid  = threadIdx.x;
    const int lane = tid & 63;
    const int wave = tid >> 6;
    const int wm   = (wave & 1) * 64;
    const int wn   = (wave >> 1) * 64;
    const int ml   = lane & 15;
    const int kq   = lane >> 4;

    const int row0 = tid >> 2;
    const int row1 = row0 + 64;
    const int kqs  = (tid & 3) ^ ((row0 >> 1) & 3);
    const short* gA0 = A  + (size_t)(m0 + row0) * 256 + kqs * 8;
    const short* gA1 = A  + (size_t)(m0 + row1) * 256 + kqs * 8;
    const short* gB0 = Wt + (size_t)(n0 + row0) * 256 + kqs * 8;
    const short* gB1 = Wt + (size_t)(n0 + row1) * 256 + kqs * 8;
    short* lA0 = As + tid * 8;
    short* lA1 = As + (256 + tid) * 8;
    short* lB0 = Bs + tid * 8;
    short* lB1 = Bs + (256 + tid) * 8;
    const bool a0ok = (m0 + row0) < MQ;
    const bool a1ok = (m0 + row1) < MQ;

    for (int k0 = 0; k0 < 256; k0 += 32) {
        if (a0ok) gld_lds16(gA0 + k0, lA0);
        if (a1ok) gld_lds16(gA1 + k0, lA1);
        gld_lds16(gB0 + k0, lB0);
        gld_lds16(gB1 + k0, lB1);
        __syncthreads();

        bf16x8 af[4], bfr[4];
#pragma unroll
        for (int ti = 0; ti < 4; ++ti) {
            const int r = wm + ti * 16 + ml;
            af[ti] = *(const bf16x8*)&As[r * 32 + ((kq ^ ((r >> 1) & 3)) << 3)];
        }
#pragma unroll
        for (int tj = 0; tj < 4; ++tj) {
            const int r = wn + tj * 16 + ml;
            bfr[tj] = *(const bf16x8*)&Bs[r * 32 + ((kq ^ ((r >> 1) & 3)) << 3)];
        }
#pragma unroll
        for (int ti = 0; ti < 4; ++ti)
#pragma unroll
            for (int tj = 0; tj < 4; ++tj)
                acc[ti][tj] = __builtin_amdgcn_mfma_f32_16x16x32_bf16(af[ti], bfr[tj], acc[ti][tj], 0, 0, 0);

        __syncthreads();
    }
}

// fused vproj + offs/logits: blockIdx.y: 0,1 -> vproj n-halves; 2,3,4 -> qkv n-thirds (N=384 padded)
__global__ __launch_bounds__(256) void gemm5_kernel(const short* __restrict__ vcat,
                                                    const short* __restrict__ qbf,
                                                    const short* __restrict__ Wt_val,
                                                    const short* __restrict__ Wt_off,
                                                    const float* __restrict__ b_val,
                                                    const float* __restrict__ b_off,
                                                    const float* __restrict__ b_attn,
                                                    short* __restrict__ vws,
                                                    float* __restrict__ offs,
                                                    float* __restrict__ lgts)
{
    __shared__ short As[128 * 32];
    __shared__ short Bs[128 * 32];

    const int y   = blockIdx.y;
    const int m0  = blockIdx.x * 128;
    const bool isv = (y < 2);
    const short* A  = isv ? vcat : qbf;
    const short* Wt = isv ? Wt_val : Wt_off;
    const int n0 = isv ? y * 128 : (y - 2) * 128;

    f32x4 acc[4][4] = {};
    gemm_core128(A, Wt, m0, n0, acc, As, Bs);

    const int tid  = threadIdx.x;
    const int lane = tid & 63;
    const int wave = tid >> 6;
    const int wm   = (wave & 1) * 64;
    const int wn   = (wave >> 1) * 64;
    const int ml   = lane & 15;
    const int kq   = lane >> 4;

#pragma unroll
    for (int tj = 0; tj < 4; ++tj) {
        const int gn = n0 + wn + tj * 16 + ml;
#pragma unroll
        for (int ti = 0; ti < 4; ++ti) {
#pragma unroll
            for (int r = 0; r < 4; ++r) {
                const int gm = m0 + wm + ti * 16 + kq * 4 + r;
                if (gm >= MQ) continue;
                const float v = acc[ti][tj][r];
                if (isv) {
                    vws[(size_t)gm * 256 + gn] = f2bf(v + b_val[gn]);
                } else {
                    if (gn < 192)      offs[(size_t)gm * 192 + gn]        = v + b_off[gn];
                    else if (gn < 288) lgts[(size_t)gm * 96 + (gn - 192)] = v + b_attn[gn - 192];
                }
            }
        }
    }
}

// output projection: A=mid(bf16) -> out fp32
__global__ __launch_bounds__(256) void ogemm_kernel(const short* __restrict__ A,
                                                    const short* __restrict__ Wt,
                                                    const float* __restrict__ bias,
                                                    float* __restrict__ C)
{
    __shared__ short As[128 * 32];
    __shared__ short Bs[128 * 32];
    const int m0 = blockIdx.y * 128;
    const int n0 = blockIdx.x * 128;

    f32x4 acc[4][4] = {};
    gemm_core128(A, Wt, m0, n0, acc, As, Bs);

    const int tid  = threadIdx.x;
    const int lane = tid & 63;
    const int wave = tid >> 6;
    const int wm   = (wave & 1) * 64;
    const int wn   = (wave >> 1) * 64;
    const int ml   = lane & 15;
    const int kq   = lane >> 4;

#pragma unroll
    for (int tj = 0; tj < 4; ++tj) {
        const int gn = n0 + wn + tj * 16 + ml;
#pragma unroll
        for (int ti = 0; ti < 4; ++ti) {
#pragma unroll
            for (int r = 0; r < 4; ++r) {
                const int gm = m0 + wm + ti * 16 + kq * 4 + r;
                if (gm >= MQ) continue;
                C[(size_t)gm * 256 + gn] = acc[ti][tj][r] + bias[gn];
            }
        }
    }
}

// ---------------- sampling: R4 config (best measured 63.6us): 4 q/block, 256 thr ----------------
__global__ __launch_bounds__(256) void sample_kernel(const short* __restrict__ vws,
                                                     const float* __restrict__ offs,
                                                     const float* __restrict__ logits,
                                                     const float* __restrict__ refp,
                                                     short* __restrict__ mid)
{
    const int q0  = blockIdx.x * 4;
    const int tid = threadIdx.x;

    __shared__ float  s_lg[4][96];
    __shared__ float  s_ref[4][6];
    __shared__ float  s_stat[4][NH][2];
    __shared__ float4 s_w[4][96];
    __shared__ int4   s_i[4][96];

    // Phase A: stage logits + refs
    for (int idx = tid; idx < 384; idx += 256) {
        const int qq = idx / 96, s = idx % 96;
        const int q = q0 + qq;
        if (q < MQ) s_lg[qq][s] = logits[(size_t)q * 96 + s];
    }
    if (tid < 24) {
        const int qq = tid / 6, j = tid % 6;
        const int q = q0 + qq;
        if (q < MQ) s_ref[qq][j] = refp[(size_t)q * 6 + j];
    }
    __syncthreads();

    // Phase B: per-head softmax stats
    if (tid < 32) {
        const int qq = tid >> 3, h = tid & 7;
        if (q0 + qq < MQ) {
            float mx = -1e30f;
#pragma unroll
            for (int i = 0; i < 12; ++i) mx = fmaxf(mx, s_lg[qq][h * 12 + i]);
            float ssum = 0.f;
#pragma unroll
            for (int i = 0; i < 12; ++i) ssum += expf(s_lg[qq][h * 12 + i] - mx);
            s_stat[qq][h][0] = mx;
            s_stat[qq][h][1] = 1.f / ssum;
        }
    }
    __syncthreads();

    // Phase C: folded corner weights + token indices
    for (int idx = tid; idx < 384; idx += 256) {
        const int qq = idx / 96, s = idx % 96;
        const int q  = q0 + qq;
        if (q >= MQ) continue;
        const int b  = q / NQ;
        const int h  = s / 12, i = s % 12;
        const int l  = i >> 2, p = i & 3;

        const int Hs[3] = {100, 50, 25};
        const int Wz[3] = {100, 50, 25};
        const int Lo[3] = {0, 10000, 12500};
        const int Wl = Wz[l], Hl = Hs[l];
        const float fW = (float)Wl, fH = (float)Hl;

        const float aw = expf(s_lg[qq][s] - s_stat[qq][h][0]) * s_stat[qq][h][1];

        const int oi = (((h * NL) + l) * NP + p) * 2;
        const float2 offp = *(const float2*)(offs + (size_t)q * 192 + oi);
        const float rx = s_ref[qq][l * 2 + 0];
        const float ry = s_ref[qq][l * 2 + 1];

        const float x = (rx + offp.x / fW) * fW - 0.5f;
        const float y = (ry + offp.y / fH) * fH - 0.5f;
        const float x0f = floorf(x), y0f = floorf(y);
        const int   x0 = (int)x0f,  y0 = (int)y0f;
        const float wx1 = x - x0f, wy1 = y - y0f;
        const float wx0 = 1.f - wx1, wy0 = 1.f - wy1;

        const bool xin0 = (x0 >= 0) && (x0 < Wl);
        const bool xin1 = (x0 + 1 >= 0) && (x0 + 1 < Wl);
        const bool yin0 = (y0 >= 0) && (y0 < Hl);
        const bool yin1 = (y0 + 1 >= 0) && (y0 + 1 < Hl);

        const int cx0 = min(max(x0, 0), Wl - 1);
        const int cx1 = min(max(x0 + 1, 0), Wl - 1);
        const int cy0 = min(max(y0, 0), Hl - 1);
        const int cy1 = min(max(y0 + 1, 0), Hl - 1);

        const int base = b * NTOK + Lo[l];
        int4 idxv;
        idxv.x = base + cy0 * Wl + cx0;
        idxv.y = base + cy0 * Wl + cx1;
        idxv.z = base + cy1 * Wl + cx0;
        idxv.w = base + cy1 * Wl + cx1;

        float4 w;
        w.x = (xin0 && yin0) ? aw * wx0 * wy0 : 0.f;
        w.y = (xin1 && yin0) ? aw * wx1 * wy0 : 0.f;
        w.z = (xin0 && yin1) ? aw * wx0 * wy1 : 0.f;
        w.w = (xin1 && yin1) ? aw * wx1 * wy1 : 0.f;

        s_w[qq][s] = w;
        s_i[qq][s] = idxv;
    }
    __syncthreads();

    // Phase D: gather-FMA, 64 threads/query, 4 bf16 channels per lane (8B loads)
    {
        const int qq = tid >> 6;
        const int q  = q0 + qq;
        if (q < MQ) {
            const int r  = tid & 63;
            const int h  = r >> 3;
            const int c4 = (r & 7) * 4;
            const int ch = h * HDIM + c4;

            float a0 = 0.f, a1 = 0.f, a2 = 0.f, a3 = 0.f;
#pragma unroll
            for (int s = 0; s < 12; ++s) {
                const float4 w  = s_w[qq][h * 12 + s];
                const int4   id = s_i[qq][h * 12 + s];
                const ushort4 u0 = *(const ushort4*)(vws + (size_t)id.x * DM + ch);
                const ushort4 u1 = *(const ushort4*)(vws + (size_t)id.y * DM + ch);
                const ushort4 u2 = *(const ushort4*)(vws + (size_t)id.z * DM + ch);
                const ushort4 u3 = *(const ushort4*)(vws + (size_t)id.w * DM + ch);
                a0 += w.x * bf2f(u0.x) + w.y * bf2f(u1.x) + w.z * bf2f(u2.x) + w.w * bf2f(u3.x);
                a1 += w.x * bf2f(u0.y) + w.y * bf2f(u1.y) + w.z * bf2f(u2.y) + w.w * bf2f(u3.y);
                a2 += w.x * bf2f(u0.z) + w.y * bf2f(u1.z) + w.z * bf2f(u2.z) + w.w * bf2f(u3.z);
                a3 += w.x * bf2f(u0.w) + w.y * bf2f(u1.w) + w.z * bf2f(u2.w) + w.w * bf2f(u3.w);
            }
            short4 o;
            o.x = f2bf(a0); o.y = f2bf(a1); o.z = f2bf(a2); o.w = f2bf(a3);
            *(short4*)(mid + (size_t)q * DM + ch) = o;
        }
    }
}

// ---------------------------------------------------------------------------------------------
extern "C" void kernel_launch(void* const* d_in, const int* in_sizes, int n_in,
                              void* d_out, int out_size, void* d_ws, size_t ws_size,
                              hipStream_t stream)
{
    const float* query  = (const float*)d_in[0];
    const float* refp   = (const float*)d_in[1];
    const float* v0     = (const float*)d_in[2];
    const float* v1     = (const float*)d_in[3];
    const float* v2     = (const float*)d_in[4];
    const float* W_val  = (const float*)d_in[5];
    const float* b_val  = (const float*)d_in[6];
    const float* W_off  = (const float*)d_in[7];
    const float* b_off  = (const float*)d_in[8];
    const float* W_attn = (const float*)d_in[9];
    const float* b_attn = (const float*)d_in[10];
    const float* W_out  = (const float*)d_in[11];
    const float* b_out  = (const float*)d_in[12];
    float* out = (float*)d_out;

    float* ws   = (float*)d_ws;
    float* offs = ws;                                    // MQ*192 f32
    float* lgts = offs + (size_t)MQ * 192;               // MQ*96 f32
    short* vws  = (short*)(lgts + (size_t)MQ * 96);      // MQ*256 bf16 (projected values)
    short* mid  = vws + (size_t)MQ * DM;                 // MQ*256 bf16
    short* qbf  = mid + (size_t)MQ * DM;                 // MQ*256 bf16
    short* vcat = qbf + (size_t)MQ * DM;                 // MQ*256 bf16 (raw values, concat layout)
    short* Wt   = vcat + (size_t)MQ * DM;                // 229376 bf16
    short* Wt_val = Wt;                                  // rows 0..255
    short* Wt_off = Wt + 65536;                          // 384 rows: off|attn|pad
    short* Wt_out = Wt + 163840;                         // 256 rows

    // 1. prep: weights->bf16 transposed + activations->bf16 (one launch)
    prep_kernel<<<1280 + 13125, 256, 0, stream>>>(W_val, W_off, W_attn, W_out,
                                                  query, v0, v1, v2, Wt, qbf, vcat);
    // 2. fused vproj + offs/logits (one launch, 5 n-tiles x 206 m-tiles)
    {
        dim3 grid((MQ + 127) / 128, 5);
        gemm5_kernel<<<grid, 256, 0, stream>>>(vcat, qbf, Wt_val, Wt_off,
                                               b_val, b_off, b_attn, vws, offs, lgts);
    }
    // 3. softmax + bilinear sampling (4 q/block, 256 thr) -> mid (bf16)
    sample_kernel<<<(MQ + 3) / 4, 256, 0, stream>>>(vws, offs, lgts, refp, mid);
    // 4. output projection -> out (fp32)
    {
        dim3 grid(2, (MQ + 127) / 128);
        ogemm_kernel<<<grid, 256, 0, stream>>>(mid, Wt_out, b_out, out);
    }
}

// Round 9
// 226.873 us; speedup vs baseline: 1.1659x; 1.0080x over previous
//
#include <hip/hip_runtime.h>
#include <hip/hip_bf16.h>
#include <math.h>

#define BATCH 2
#define NQ    13125
#define MQ    26250   // BATCH*NQ
#define DM    256
#define NH    8
#define HDIM  32
#define NL    3
#define NP    4
#define NTOK  13125   // value tokens per batch (10000+2500+625)

typedef __attribute__((ext_vector_type(8))) short bf16x8;
typedef __attribute__((ext_vector_type(4))) float f32x4;

__device__ __forceinline__ short f2bf(float f) {
    unsigned u = __float_as_uint(f);
    unsigned r = (u + 0x7FFFu + ((u >> 16) & 1u)) >> 16;
    return (short)r;
}
__device__ __forceinline__ float bf2f(unsigned short u) {
    return __uint_as_float((unsigned)u << 16);
}

// async global->LDS, 16B per lane. LDS dest must be wave-uniform base + lane*16.
__device__ __forceinline__ void gld_lds16(const short* g, short* l) {
    __builtin_amdgcn_global_load_lds(
        (const __attribute__((address_space(1))) unsigned int*)g,
        (__attribute__((address_space(3))) unsigned int*)l, 16, 0, 0);
}

// ---------------- weight prep ONLY: Wt[n][k] bf16 <- W[k][n] fp32, + zero pad ----------------
// Wt layout: Wt_val rows 0..255 | Wt_off 384 rows (off 0..191, attn 192..287, pad 288..383) | Wt_out
__global__ __launch_bounds__(256) void wprep_kernel(const float* __restrict__ Wv,
                                                    const float* __restrict__ Wo,
                                                    const float* __restrict__ Wa,
                                                    const float* __restrict__ Wu,
                                                    short* __restrict__ Wt)
{
    const int bid = blockIdx.x;
    const int w  = bid >> 8;
    const int Ns[5]   = {256, 192, 96, 256, 96};
    const int Offs[5] = {0, 65536, 114688, 163840, 139264};
    const int N = Ns[w];
    const int flat = (bid & 255) * 256 + threadIdx.x;
    const int n = flat >> 8, k = flat & 255;
    if (n >= N) return;
    if (w == 4) { Wt[139264 + n * 256 + k] = 0; return; }
    const float* W = (w == 0) ? Wv : ((w == 1) ? Wo : ((w == 2) ? Wa : Wu));
    Wt[Offs[w] + n * 256 + k] = f2bf(W[k * N + n]);
}

// ---------------- fused vproj + offs/logits GEMM: A read from fp32 sources, convert-on-stage ----
// 128(M)x128(N) tiles; blockIdx.y: 0,1 -> vproj n-halves; 2,3,4 -> qkv n-thirds (N padded 384).
// A-staging: manual, thread t owns row r=t>>1 half h=t&1; 16 fp32 -> 16 bf16 -> 2x ds_write_b128,
// XOR k-granule swizzle p = kq ^ ((r>>1)&3) (matches MFMA-read formula).
// B-staging: glds width-16 from pre-transposed bf16 Wt (R8 path).
__global__ __launch_bounds__(256) void gemm5_kernel(const float* __restrict__ query,
                                                    const float* __restrict__ v0,
                                                    const float* __restrict__ v1,
                                                    const float* __restrict__ v2,
                                                    const short* __restrict__ Wt_val,
                                                    const short* __restrict__ Wt_off,
                                                    const float* __restrict__ b_val,
                                                    const float* __restrict__ b_off,
                                                    const float* __restrict__ b_attn,
                                                    short* __restrict__ vws,
                                                    float* __restrict__ offs,
                                                    float* __restrict__ lgts)
{
    __shared__ short As[128 * 32];
    __shared__ short Bs[128 * 32];

    const int tid  = threadIdx.x;
    const int y    = blockIdx.y;
    const int m0   = blockIdx.x * 128;
    const bool isv = (y < 2);
    const short* Wt = isv ? Wt_val : Wt_off;
    const int n0 = isv ? y * 128 : (y - 2) * 128;

    // ---- A source row pointer (computed once; clamped so OOB rows read finite garbage) ----
    const int r  = tid >> 1;           // staging row 0..127
    const int h  = tid & 1;            // k-half within 32-chunk
    const int gm = m0 + r;
    const int gmc = (gm < MQ) ? gm : (MQ - 1);
    const float* Arow;
    if (isv) {
        const int b  = gmc / NTOK;
        const int rr = gmc % NTOK;
        if (rr < 10000)      Arow = v0 + (size_t)(b * 10000 + rr) * 256;
        else if (rr < 12500) Arow = v1 + (size_t)(b * 2500 + rr - 10000) * 256;
        else                 Arow = v2 + (size_t)(b * 625 + rr - 12500) * 256;
    } else {
        Arow = query + (size_t)gmc * 256;
    }
    const int pA0 = ((h * 2 + 0) ^ ((r >> 1) & 3)) << 3;
    const int pA1 = ((h * 2 + 1) ^ ((r >> 1) & 3)) << 3;
    short* lAr = As + r * 32;

    // ---- B staging (glds) ----
    const int row0 = tid >> 2;
    const int row1 = row0 + 64;
    const int kqs  = (tid & 3) ^ ((row0 >> 1) & 3);
    const short* gB0 = Wt + (size_t)(n0 + row0) * 256 + kqs * 8;
    const short* gB1 = Wt + (size_t)(n0 + row1) * 256 + kqs * 8;
    short* lB0 = Bs + tid * 8;
    short* lB1 = Bs + (256 + tid) * 8;

    const int lane = tid & 63;
    const int wave = tid >> 6;
    const int wm   = (wave & 1) * 64;
    const int wn   = (wave >> 1) * 64;
    const int ml   = lane & 15;
    const int kq   = lane >> 4;

    f32x4 acc[4][4] = {};

    for (int k0 = 0; k0 < 256; k0 += 32) {
        gld_lds16(gB0 + k0, lB0);
        gld_lds16(gB1 + k0, lB1);

        const float4 a0 = *(const float4*)(Arow + k0 + h * 16 + 0);
        const float4 a1 = *(const float4*)(Arow + k0 + h * 16 + 4);
        const float4 a2 = *(const float4*)(Arow + k0 + h * 16 + 8);
        const float4 a3 = *(const float4*)(Arow + k0 + h * 16 + 12);
        union { bf16x8 v; short s[8]; } t0, t1;
        t0.s[0] = f2bf(a0.x); t0.s[1] = f2bf(a0.y); t0.s[2] = f2bf(a0.z); t0.s[3] = f2bf(a0.w);
        t0.s[4] = f2bf(a1.x); t0.s[5] = f2bf(a1.y); t0.s[6] = f2bf(a1.z); t0.s[7] = f2bf(a1.w);
        t1.s[0] = f2bf(a2.x); t1.s[1] = f2bf(a2.y); t1.s[2] = f2bf(a2.z); t1.s[3] = f2bf(a2.w);
        t1.s[4] = f2bf(a3.x); t1.s[5] = f2bf(a3.y); t1.s[6] = f2bf(a3.z); t1.s[7] = f2bf(a3.w);
        *(bf16x8*)(lAr + pA0) = t0.v;
        *(bf16x8*)(lAr + pA1) = t1.v;

        __syncthreads();

        bf16x8 af[4], bfr[4];
#pragma unroll
        for (int ti = 0; ti < 4; ++ti) {
            const int rr = wm + ti * 16 + ml;
            af[ti] = *(const bf16x8*)&As[rr * 32 + ((kq ^ ((rr >> 1) & 3)) << 3)];
        }
#pragma unroll
        for (int tj = 0; tj < 4; ++tj) {
            const int rr = wn + tj * 16 + ml;
            bfr[tj] = *(const bf16x8*)&Bs[rr * 32 + ((kq ^ ((rr >> 1) & 3)) << 3)];
        }
#pragma unroll
        for (int ti = 0; ti < 4; ++ti)
#pragma unroll
            for (int tj = 0; tj < 4; ++tj)
                acc[ti][tj] = __builtin_amdgcn_mfma_f32_16x16x32_bf16(af[ti], bfr[tj], acc[ti][tj], 0, 0, 0);

        __syncthreads();
    }

    // C/D layout: col = lane&15, row = (lane>>4)*4 + reg
#pragma unroll
    for (int tj = 0; tj < 4; ++tj) {
        const int gn = n0 + wn + tj * 16 + ml;
#pragma unroll
        for (int ti = 0; ti < 4; ++ti) {
#pragma unroll
            for (int rr = 0; rr < 4; ++rr) {
                const int gmo = m0 + wm + ti * 16 + kq * 4 + rr;
                if (gmo >= MQ) continue;
                const float v = acc[ti][tj][rr];
                if (isv) {
                    vws[(size_t)gmo * 256 + gn] = f2bf(v + b_val[gn]);
                } else {
                    if (gn < 192)      offs[(size_t)gmo * 192 + gn]        = v + b_off[gn];
                    else if (gn < 288) lgts[(size_t)gmo * 96 + (gn - 192)] = v + b_attn[gn - 192];
                }
            }
        }
    }
}

// ---------------- output projection (R8 internals): A=mid(bf16) glds -> out fp32 ----------------
__device__ __forceinline__ void gemm_core128(const short* __restrict__ A,
                                             const short* __restrict__ Wt,
                                             int m0, int n0,
                                             f32x4 (&acc)[4][4],
                                             short* As, short* Bs)
{
    const int tid  = threadIdx.x;
    const int lane = tid & 63;
    const int wave = tid >> 6;
    const int wm   = (wave & 1) * 64;
    const int wn   = (wave >> 1) * 64;
    const int ml   = lane & 15;
    const int kq   = lane >> 4;

    const int row0 = tid >> 2;
    const int row1 = row0 + 64;
    const int kqs  = (tid & 3) ^ ((row0 >> 1) & 3);
    const short* gA0 = A  + (size_t)(m0 + row0) * 256 + kqs * 8;
    const short* gA1 = A  + (size_t)(m0 + row1) * 256 + kqs * 8;
    const short* gB0 = Wt + (size_t)(n0 + row0) * 256 + kqs * 8;
    const short* gB1 = Wt + (size_t)(n0 + row1) * 256 + kqs * 8;
    short* lA0 = As + tid * 8;
    short* lA1 = As + (256 + tid) * 8;
    short* lB0 = Bs + tid * 8;
    short* lB1 = Bs + (256 + tid) * 8;
    const bool a0ok = (m0 + row0) < MQ;
    const bool a1ok = (m0 + row1) < MQ;

    for (int k0 = 0; k0 < 256; k0 += 32) {
        if (a0ok) gld_lds16(gA0 + k0, lA0);
        if (a1ok) gld_lds16(gA1 + k0, lA1);
        gld_lds16(gB0 + k0, lB0);
        gld_lds16(gB1 + k0, lB1);
        __syncthreads();

        bf16x8 af[4], bfr[4];
#pragma unroll
        for (int ti = 0; ti < 4; ++ti) {
            const int r = wm + ti * 16 + ml;
            af[ti] = *(const bf16x8*)&As[r * 32 + ((kq ^ ((r >> 1) & 3)) << 3)];
        }
#pragma unroll
        for (int tj = 0; tj < 4; ++tj) {
            const int r = wn + tj * 16 + ml;
            bfr[tj] = *(const bf16x8*)&Bs[r * 32 + ((kq ^ ((r >> 1) & 3)) << 3)];
        }
#pragma unroll
        for (int ti = 0; ti < 4; ++ti)
#pragma unroll
            for (int tj = 0; tj < 4; ++tj)
                acc[ti][tj] = __builtin_amdgcn_mfma_f32_16x16x32_bf16(af[ti], bfr[tj], acc[ti][tj], 0, 0, 0);

        __syncthreads();
    }
}

__global__ __launch_bounds__(256) void ogemm_kernel(const short* __restrict__ A,
                                                    const short* __restrict__ Wt,
                                                    const float* __restrict__ bias,
                                                    float* __restrict__ C)
{
    __shared__ short As[128 * 32];
    __shared__ short Bs[128 * 32];
    const int m0 = blockIdx.y * 128;
    const int n0 = blockIdx.x * 128;

    f32x4 acc[4][4] = {};
    gemm_core128(A, Wt, m0, n0, acc, As, Bs);

    const int tid  = threadIdx.x;
    const int lane = tid & 63;
    const int wave = tid >> 6;
    const int wm   = (wave & 1) * 64;
    const int wn   = (wave >> 1) * 64;
    const int ml   = lane & 15;
    const int kq   = lane >> 4;

#pragma unroll
    for (int tj = 0; tj < 4; ++tj) {
        const int gn = n0 + wn + tj * 16 + ml;
#pragma unroll
        for (int ti = 0; ti < 4; ++ti) {
#pragma unroll
            for (int r = 0; r < 4; ++r) {
                const int gm = m0 + wm + ti * 16 + kq * 4 + r;
                if (gm >= MQ) continue;
                C[(size_t)gm * 256 + gn] = acc[ti][tj][r] + bias[gn];
            }
        }
    }
}

// ---------------- sampling: R8/R4 best config (63.6us): 4 q/block, 256 thr ----------------
__global__ __launch_bounds__(256) void sample_kernel(const short* __restrict__ vws,
                                                     const float* __restrict__ offs,
                                                     const float* __restrict__ logits,
                                                     const float* __restrict__ refp,
                                                     short* __restrict__ mid)
{
    const int q0  = blockIdx.x * 4;
    const int tid = threadIdx.x;

    __shared__ float  s_lg[4][96];
    __shared__ float  s_ref[4][6];
    __shared__ float  s_stat[4][NH][2];
    __shared__ float4 s_w[4][96];
    __shared__ int4   s_i[4][96];

    // Phase A: stage logits + refs
    for (int idx = tid; idx < 384; idx += 256) {
        const int qq = idx / 96, s = idx % 96;
        const int q = q0 + qq;
        if (q < MQ) s_lg[qq][s] = logits[(size_t)q * 96 + s];
    }
    if (tid < 24) {
        const int qq = tid / 6, j = tid % 6;
        const int q = q0 + qq;
        if (q < MQ) s_ref[qq][j] = refp[(size_t)q * 6 + j];
    }
    __syncthreads();

    // Phase B: per-head softmax stats
    if (tid < 32) {
        const int qq = tid >> 3, h = tid & 7;
        if (q0 + qq < MQ) {
            float mx = -1e30f;
#pragma unroll
            for (int i = 0; i < 12; ++i) mx = fmaxf(mx, s_lg[qq][h * 12 + i]);
            float ssum = 0.f;
#pragma unroll
            for (int i = 0; i < 12; ++i) ssum += expf(s_lg[qq][h * 12 + i] - mx);
            s_stat[qq][h][0] = mx;
            s_stat[qq][h][1] = 1.f / ssum;
        }
    }
    __syncthreads();

    // Phase C: folded corner weights + token indices
    for (int idx = tid; idx < 384; idx += 256) {
        const int qq = idx / 96, s = idx % 96;
        const int q  = q0 + qq;
        if (q >= MQ) continue;
        const int b  = q / NQ;
        const int h  = s / 12, i = s % 12;
        const int l  = i >> 2, p = i & 3;

        const int Hs[3] = {100, 50, 25};
        const int Wz[3] = {100, 50, 25};
        const int Lo[3] = {0, 10000, 12500};
        const int Wl = Wz[l], Hl = Hs[l];
        const float fW = (float)Wl, fH = (float)Hl;

        const float aw = expf(s_lg[qq][s] - s_stat[qq][h][0]) * s_stat[qq][h][1];

        const int oi = (((h * NL) + l) * NP + p) * 2;
        const float2 offp = *(const float2*)(offs + (size_t)q * 192 + oi);
        const float rx = s_ref[qq][l * 2 + 0];
        const float ry = s_ref[qq][l * 2 + 1];

        const float x = (rx + offp.x / fW) * fW - 0.5f;
        const float y = (ry + offp.y / fH) * fH - 0.5f;
        const float x0f = floorf(x), y0f = floorf(y);
        const int   x0 = (int)x0f,  y0 = (int)y0f;
        const float wx1 = x - x0f, wy1 = y - y0f;
        const float wx0 = 1.f - wx1, wy0 = 1.f - wy1;

        const bool xin0 = (x0 >= 0) && (x0 < Wl);
        const bool xin1 = (x0 + 1 >= 0) && (x0 + 1 < Wl);
        const bool yin0 = (y0 >= 0) && (y0 < Hl);
        const bool yin1 = (y0 + 1 >= 0) && (y0 + 1 < Hl);

        const int cx0 = min(max(x0, 0), Wl - 1);
        const int cx1 = min(max(x0 + 1, 0), Wl - 1);
        const int cy0 = min(max(y0, 0), Hl - 1);
        const int cy1 = min(max(y0 + 1, 0), Hl - 1);

        const int base = b * NTOK + Lo[l];
        int4 idxv;
        idxv.x = base + cy0 * Wl + cx0;
        idxv.y = base + cy0 * Wl + cx1;
        idxv.z = base + cy1 * Wl + cx0;
        idxv.w = base + cy1 * Wl + cx1;

        float4 w;
        w.x = (xin0 && yin0) ? aw * wx0 * wy0 : 0.f;
        w.y = (xin1 && yin0) ? aw * wx1 * wy0 : 0.f;
        w.z = (xin0 && yin1) ? aw * wx0 * wy1 : 0.f;
        w.w = (xin1 && yin1) ? aw * wx1 * wy1 : 0.f;

        s_w[qq][s] = w;
        s_i[qq][s] = idxv;
    }
    __syncthreads();

    // Phase D: gather-FMA, 64 threads/query, 4 bf16 channels per lane (8B loads)
    {
        const int qq = tid >> 6;
        const int q  = q0 + qq;
        if (q < MQ) {
            const int r  = tid & 63;
            const int h  = r >> 3;
            const int c4 = (r & 7) * 4;
            const int ch = h * HDIM + c4;

            float a0 = 0.f, a1 = 0.f, a2 = 0.f, a3 = 0.f;
#pragma unroll
            for (int s = 0; s < 12; ++s) {
                const float4 w  = s_w[qq][h * 12 + s];
                const int4   id = s_i[qq][h * 12 + s];
                const ushort4 u0 = *(const ushort4*)(vws + (size_t)id.x * DM + ch);
                const ushort4 u1 = *(const ushort4*)(vws + (size_t)id.y * DM + ch);
                const ushort4 u2 = *(const ushort4*)(vws + (size_t)id.z * DM + ch);
                const ushort4 u3 = *(const ushort4*)(vws + (size_t)id.w * DM + ch);
                a0 += w.x * bf2f(u0.x) + w.y * bf2f(u1.x) + w.z * bf2f(u2.x) + w.w * bf2f(u3.x);
                a1 += w.x * bf2f(u0.y) + w.y * bf2f(u1.y) + w.z * bf2f(u2.y) + w.w * bf2f(u3.y);
                a2 += w.x * bf2f(u0.z) + w.y * bf2f(u1.z) + w.z * bf2f(u2.z) + w.w * bf2f(u3.z);
                a3 += w.x * bf2f(u0.w) + w.y * bf2f(u1.w) + w.z * bf2f(u2.w) + w.w * bf2f(u3.w);
            }
            short4 o;
            o.x = f2bf(a0); o.y = f2bf(a1); o.z = f2bf(a2); o.w = f2bf(a3);
            *(short4*)(mid + (size_t)q * DM + ch) = o;
        }
    }
}

// ---------------------------------------------------------------------------------------------
extern "C" void kernel_launch(void* const* d_in, const int* in_sizes, int n_in,
                              void* d_out, int out_size, void* d_ws, size_t ws_size,
                              hipStream_t stream)
{
    const float* query  = (const float*)d_in[0];
    const float* refp   = (const float*)d_in[1];
    const float* v0     = (const float*)d_in[2];
    const float* v1     = (const float*)d_in[3];
    const float* v2     = (const float*)d_in[4];
    const float* W_val  = (const float*)d_in[5];
    const float* b_val  = (const float*)d_in[6];
    const float* W_off  = (const float*)d_in[7];
    const float* b_off  = (const float*)d_in[8];
    const float* W_attn = (const float*)d_in[9];
    const float* b_attn = (const float*)d_in[10];
    const float* W_out  = (const float*)d_in[11];
    const float* b_out  = (const float*)d_in[12];
    float* out = (float*)d_out;

    float* ws   = (float*)d_ws;
    float* offs = ws;                                    // MQ*192 f32
    float* lgts = offs + (size_t)MQ * 192;               // MQ*96 f32
    short* vws  = (short*)(lgts + (size_t)MQ * 96);      // MQ*256 bf16 (projected values)
    short* mid  = vws + (size_t)MQ * DM;                 // MQ*256 bf16
    short* Wt   = mid + (size_t)MQ * DM;                 // 229376 bf16
    short* Wt_val = Wt;                                  // rows 0..255
    short* Wt_off = Wt + 65536;                          // 384 rows: off|attn|pad
    short* Wt_out = Wt + 163840;                         // 256 rows

    // 1. weights -> bf16 transposed (+ zero pad)
    wprep_kernel<<<1280, 256, 0, stream>>>(W_val, W_off, W_attn, W_out, Wt);
    // 2. fused vproj + offs/logits, A direct from fp32 inputs (convert-on-stage)
    {
        dim3 grid((MQ + 127) / 128, 5);
        gemm5_kernel<<<grid, 256, 0, stream>>>(query, v0, v1, v2, Wt_val, Wt_off,
                                               b_val, b_off, b_attn, vws, offs, lgts);
    }
    // 3. softmax + bilinear sampling (4 q/block, 256 thr) -> mid (bf16)
    sample_kernel<<<(MQ + 3) / 4, 256, 0, stream>>>(vws, offs, lgts, refp, mid);
    // 4. output projection -> out (fp32)
    {
        dim3 grid(2, (MQ + 127) / 128);
        ogemm_kernel<<<grid, 256, 0, stream>>>(mid, Wt_out, b_out, out);
    }
}